// Round 6
// baseline (662.801 us; speedup 1.0000x reference)
//
#include <hip/hip_runtime.h>
#include <hip/hip_bf16.h>

typedef __attribute__((ext_vector_type(8))) short short8;
typedef __attribute__((ext_vector_type(4))) short short4v;
typedef __attribute__((ext_vector_type(4))) float floatx4;

__device__ __forceinline__ float b2f(ushort u) {
  unsigned x = ((unsigned)u) << 16;
  return __builtin_bit_cast(float, x);
}
__device__ __forceinline__ ushort f2b(float f) {
  unsigned x = __builtin_bit_cast(unsigned, f);
  x += 0x7fffu + ((x >> 16) & 1u);
  return (ushort)(x >> 16);
}

__device__ __forceinline__ void gload_lds16(const void* g, void* l) {
  __builtin_amdgcn_global_load_lds(
      (const __attribute__((address_space(1))) unsigned int*)g,
      (__attribute__((address_space(3))) unsigned int*)l, 16, 0, 0);
}

// ---------------- f32 -> bf16 conversion ----------------
__global__ __launch_bounds__(256) void cvt_kernel(const float* __restrict__ in,
                                                  ushort* __restrict__ out, long n) {
  long i0 = ((long)blockIdx.x * 256 + threadIdx.x) * 4;
  long stride = (long)gridDim.x * 256 * 4;
  for (long i = i0; i < n; i += stride) {
    float4 v = *(const float4*)(in + i);
    ushort4 u;
    u.x = f2b(v.x); u.y = f2b(v.y); u.z = f2b(v.z); u.w = f2b(v.w);
    *(ushort4*)(out + i) = u;
  }
}

// ---------------- counted-vmcnt 256x128 GEMM: C[M,N] = A[M,K] * B[N,K]^T ----------
// 8 waves (2Mx4N), BK=64, 3-buffer ring (144KB LDS), prefetch depth 2.
// Per iter: stage tile T+2 (6 loads/thread), compute tile T, then
// s_waitcnt vmcnt(6) lgkmcnt(0) + raw s_barrier: waits ONLY for tile T+1
// (issued a full iteration earlier) while T+2's loads fly across the barrier.
// lgkmcnt(0) pre-barrier closes the WAR on the buffer re-staged next iter.
// Row-XOR chunk swizzle both sides (byte ^= (row&7)<<4) -> 0 bank conflicts.
template <int BN, int OUTBF16>
__global__ __launch_bounds__(512, 2)
void gemm_pipe(const ushort* __restrict__ A, const ushort* __restrict__ B,
               float* __restrict__ Cf, ushort* __restrict__ Cb,
               int M, int N, int K) {
  constexpr int BNF = BN / 64;                      // B frags per wave (wave N = BN/4)
  __shared__ __align__(16) ushort sA[3][256 * 64];  // [buf][row*64 + k]
  __shared__ __align__(16) ushort sB[3][BN * 64];
  const int t = threadIdx.x;
  const int lane = t & 63;
  const int L = lane & 15, g = lane >> 4;
  const int w = t >> 6;
  const int wr = w >> 2, wc = w & 3;   // 2 x 4 wave grid; per-wave C = 128 x BN/4
  const int ntn = N / BN;
  const int nwg = gridDim.x;
  const int wg = blockIdx.x;
  const int swz = (wg & 7) * (nwg >> 3) + (wg >> 3);  // bijective: nwg % 8 == 0
  const int m0 = (swz / ntn) << 8;
  const int n0 = (swz % ntn) * BN;

  floatx4 acc[8][BNF];
#pragma unroll
  for (int i = 0; i < 8; i++)
#pragma unroll
    for (int j = 0; j < BNF; j++) acc[i][j] = (floatx4)(0.0f);

  const ushort* Ab = A + (size_t)m0 * K;
  const ushort* Bb = B + (size_t)n0 * K;

  // stage one full K-tile (256 rows A + BN rows B, 64 k): 4 + BN/64 loads/thread
  auto stage_tile = [&](const ushort* Ag, const ushort* Bg, int buf) {
#pragma unroll
    for (int j = 0; j < 4; j++) {
      const int c = j * 512 + t;            // 0..2047 16B chunks
      const int row = c >> 3, ch = c & 7;
      const int kc = ch ^ (row & 7);        // source-side swizzle
      gload_lds16(Ag + (size_t)row * K + kc * 8, (char*)&sA[buf][0] + c * 16);
    }
#pragma unroll
    for (int j = 0; j < BN / 64; j++) {
      const int c = j * 512 + t;            // 0..BN*8-1
      const int row = c >> 3, ch = c & 7;
      const int kc = ch ^ (row & 7);
      gload_lds16(Bg + (size_t)row * K + kc * 8, (char*)&sB[buf][0] + c * 16);
    }
  };
  // frag reads with matching XOR (read-side swizzle)
  auto rdA = [&](int buf, int mh, int kc16, short8* dst) {
#pragma unroll
    for (int i = 0; i < 4; i++) {
      const int row = wr * 128 + mh * 64 + i * 16 + L;
      const int ch = (kc16 * 4 + g) ^ (row & 7);
      dst[i] = *(const short8*)((const char*)&sA[buf][0] + row * 128 + ch * 16);
    }
  };
  auto rdB = [&](int buf, int kc16, short8* dst) {
#pragma unroll
    for (int i = 0; i < BNF; i++) {
      const int row = wc * (BN / 4) + i * 16 + L;
      const int ch = (kc16 * 4 + g) ^ (row & 7);
      dst[i] = *(const short8*)((const char*)&sB[buf][0] + row * 128 + ch * 16);
    }
  };

  short8 a0[4], a1[4], b0[BNF], b1[BNF];

  auto mfmaN = [&](short8* af, short8* bf, int accbase, int cnt) {
    __builtin_amdgcn_s_setprio(1);
    for (int i = 0; i < cnt; i++)
#pragma unroll
      for (int nf = 0; nf < BNF; nf++)
        acc[accbase + i][nf] =
            __builtin_amdgcn_mfma_f32_16x16x32_bf16(af[i], bf[nf], acc[accbase + i][nf], 0, 0, 0);
    __builtin_amdgcn_s_setprio(0);
  };

  const int NT = K >> 6;
  // prologue: stage tiles 0 and 1, wait only for tile 0 (vmcnt(6)), preload frags
  stage_tile(Ab, Bb, 0);
  stage_tile(Ab + 64, Bb + 64, 1);
  asm volatile("s_waitcnt vmcnt(6)" ::: "memory");
  __builtin_amdgcn_s_barrier();
  __builtin_amdgcn_sched_barrier(0);
  rdA(0, 0, 0, a0);
  rdB(0, 0, b0);

  int bp = 0;  // buffer holding tile T
  for (int T = 0; T < NT; ++T) {
    const int bq = (bp == 2) ? 0 : bp + 1;  // buffer of tile T+1
    const int bs = (bq == 2) ? 0 : bq + 1;  // buffer for tile T+2
    if (T + 2 < NT)
      stage_tile(Ab + (size_t)(T + 2) * 64, Bb + (size_t)(T + 2) * 64, bs);
    rdA(bp, 1, 0, a1);               // reads overlap mfma below (prev-phase regs)
    mfmaN(a0, b0, 0, 4);             // (kc0, mh0)
    rdA(bp, 0, 1, a0);
    rdB(bp, 1, b1);
    mfmaN(a1, b0, 4, 4);             // (kc0, mh1)
    rdA(bp, 1, 1, a1);
    mfmaN(a0, b1, 0, 4);             // (kc1, mh0)
    mfmaN(a1, b1, 4, 2);             // (kc1, mh1) first half
    if (T + 1 < NT) {
      // counted wait: tile T+1 complete (oldest 6 loads), T+2's 6 stay in flight;
      // lgkmcnt(0) drains this tile's ds_reads before the buffer is re-staged.
      if (T + 2 < NT)
        asm volatile("s_waitcnt vmcnt(6) lgkmcnt(0)" ::: "memory");
      else
        asm volatile("s_waitcnt vmcnt(0) lgkmcnt(0)" ::: "memory");
      __builtin_amdgcn_s_barrier();
      __builtin_amdgcn_sched_barrier(0);
      rdA(bq, 0, 0, a0);             // next tile's first-phase frags
      rdB(bq, 0, b0);
    }
    mfmaN(a1 + 2, b1, 6, 2);         // (kc1, mh1) second half covers the q-reads
    bp = bq;
  }

#pragma unroll
  for (int mf = 0; mf < 8; mf++)
#pragma unroll
    for (int nf = 0; nf < BNF; nf++)
#pragma unroll
      for (int r = 0; r < 4; r++) {
        const int row = m0 + wr * 128 + mf * 16 + g * 4 + r;
        const int col = n0 + wc * (BN / 4) + nf * 16 + L;
        if (OUTBF16)
          Cb[(size_t)row * N + col] = f2b(acc[mf][nf][r]);
        else
          Cf[(size_t)row * N + col] = acc[mf][nf][r];
      }
}

// ---------------- RoPE + split qkv -> Q[B,H,T,D], K[B,HK,T,D] ----------------
__global__ __launch_bounds__(256)
void rope_kernel(const ushort* __restrict__ qkv, const float* __restrict__ cosp,
                 const float* __restrict__ sinp, ushort* __restrict__ Qo,
                 ushort* __restrict__ Ko) {
  const int row = blockIdx.x;            // b*2048 + t
  const int b = row >> 11, tt = row & 2047;
  const int i = threadIdx.x;
  const ushort* qr = qkv + (size_t)row * 6144;

  const int jb = (i & 7) * 8;            // d offset within lower half [0,64)
  float cs[8], sn[8];
  *(float4*)&cs[0] = *(const float4*)(cosp + tt * 128 + jb);
  *(float4*)&cs[4] = *(const float4*)(cosp + tt * 128 + jb + 4);
  *(float4*)&sn[0] = *(const float4*)(sinp + tt * 128 + jb);
  *(float4*)&sn[4] = *(const float4*)(sinp + tt * 128 + jb + 4);

  {  // Q: 32 heads x 8 chunks -> 256 threads
    const int hh = i >> 3;
    short8 lo = *(const short8*)(qr + hh * 128 + jb);
    short8 hi = *(const short8*)(qr + hh * 128 + 64 + jb);
    short8 olo, ohi;
#pragma unroll
    for (int e = 0; e < 8; e++) {
      float fl = b2f((ushort)lo[e]), fh = b2f((ushort)hi[e]);
      olo[e] = (short)f2b(fl * cs[e] - fh * sn[e]);
      ohi[e] = (short)f2b(fh * cs[e] + fl * sn[e]);
    }
    ushort* dst = Qo + ((size_t)(b * 32 + hh) * 2048 + tt) * 128 + jb;
    *(short8*)dst = olo;
    *(short8*)(dst + 64) = ohi;
  }
  if (i < 64) {  // K: 8 kv-heads x 8 chunks
    const int hkk = i >> 3;
    short8 lo = *(const short8*)(qr + 4096 + hkk * 128 + jb);
    short8 hi = *(const short8*)(qr + 4096 + hkk * 128 + 64 + jb);
    short8 olo, ohi;
#pragma unroll
    for (int e = 0; e < 8; e++) {
      float fl = b2f((ushort)lo[e]), fh = b2f((ushort)hi[e]);
      olo[e] = (short)f2b(fl * cs[e] - fh * sn[e]);
      ohi[e] = (short)f2b(fh * cs[e] + fl * sn[e]);
    }
    ushort* dst = Ko + ((size_t)(b * 8 + hkk) * 2048 + tt) * 128 + jb;
    *(short8*)dst = olo;
    *(short8*)(dst + 64) = ohi;
  }
}

// ---------------- V transpose: qkv V slice -> Vt[B,HK,D,T] ----------------
__global__ __launch_bounds__(256)
void vtrans_kernel(const ushort* __restrict__ qkv, ushort* __restrict__ Vt) {
  // grid: B * HK * (T/64) = 512
  const int bx = blockIdx.x;
  const int t0 = (bx & 31) * 64;
  const int hk = (bx >> 5) & 7;
  const int b = bx >> 8;
  const int i = threadIdx.x;
  const int tq = i & 15;           // t-quad within 64
  const int dn = i >> 4;           // d-octet (16 of them)
  const ushort* src = qkv + ((size_t)(b * 2048 + t0 + tq * 4)) * 6144 + 5120 + hk * 128 + dn * 8;
  short8 v0 = *(const short8*)(src);
  short8 v1 = *(const short8*)(src + 6144);
  short8 v2 = *(const short8*)(src + 12288);
  short8 v3 = *(const short8*)(src + 18432);
  ushort* dst = Vt + ((size_t)(b * 8 + hk) * 128 + dn * 8) * 2048 + t0 + tq * 4;
#pragma unroll
  for (int e = 0; e < 8; e++) {
    short4v pk;
    pk[0] = v0[e]; pk[1] = v1[e]; pk[2] = v2[e]; pk[3] = v3[e];
    *(short4v*)(dst + (size_t)e * 2048) = pk;
  }
}

// ---------------- causal GQA flash attention ----------------
// 512 blocks: (b, h, pair). Block does q-tiles qtA=pair, qtB=15-pair sequentially
// over a single double-buffered KV prefetch sequence (34 x KVBLK=64 tiles, uniform).
#define ATT_SCALE 0.08838834764831845f

__global__ __launch_bounds__(256, 2)
void attn_kernel(const ushort* __restrict__ Q, const ushort* __restrict__ Kg,
                 const ushort* __restrict__ Vtg, ushort* __restrict__ O) {
  __shared__ __align__(16) ushort Klds[2][64 * 128];   // [kv][d], chunk-XOR swizzled
  __shared__ __align__(16) ushort Vlds[2][128 * 64];   // [d][kv], chunk-XOR swizzled
  __shared__ __align__(16) ushort Plds[4][32 * 64];    // per-wave P, col^(r<<4) swizzle
  const int t = threadIdx.x, lane = t & 63, w = t >> 6;
  const int bx = blockIdx.x;
  const int pair = bx & 7;
  const int h = (bx >> 3) & 31;
  const int b = bx >> 8;
  const int hk = h >> 2;
  const int qtA = pair, qtB = 15 - pair;
  const int nA = (qtA + 1) * 2, nB = (qtB + 1) * 2;
  const int total = nA + nB;  // 34

  const ushort* Qp = Q + ((size_t)(b * 32 + h) * 2048) * 128;
  const ushort* Kp = Kg + ((size_t)(b * 8 + hk) * 2048) * 128;
  const ushort* Vp = Vtg + ((size_t)(b * 8 + hk) * 128) * 2048;

  const int L = lane & 15, g = lane >> 4;

  auto stage = [&](int s) {
    const int tt = (s < nA) ? s : s - nA;
    const int kv0 = tt * 64;
    ushort* Kd = Klds[s & 1];
    ushort* Vd = Vlds[s & 1];
#pragma unroll
    for (int j = 0; j < 4; j++) {
      const int c = j * 256 + t;
      const int krow = c >> 4, kcol = c & 15;
      gload_lds16(Kp + (size_t)(kv0 + krow) * 128 + ((kcol ^ (krow & 15)) << 3),
                  (char*)Kd + c * 16);
    }
#pragma unroll
    for (int j = 0; j < 4; j++) {
      const int c = j * 256 + t;
      const int d = c >> 3, tc = c & 7;
      gload_lds16(Vp + (size_t)d * 2048 + kv0 + ((tc ^ (d & 7)) << 3),
                  (char*)Vd + c * 16);
    }
  };

  short8 qf[2][4];
  floatx4 o[2][8];
  float mrun[2][4], lrun[2][4];

  auto init_pass = [&](int qw) {
#pragma unroll
    for (int m = 0; m < 2; m++) {
#pragma unroll
      for (int kc = 0; kc < 4; kc++)
        qf[m][kc] = *(const short8*)(Qp + (size_t)(qw + m * 16 + L) * 128 + kc * 32 + g * 8);
#pragma unroll
      for (int dt = 0; dt < 8; dt++) o[m][dt] = (floatx4)(0.0f);
#pragma unroll
      for (int r = 0; r < 4; r++) { mrun[m][r] = -3.0e38f; lrun[m][r] = 0.0f; }
    }
  };

  auto compute = [&](int tt, int bsel, int qw) {
    const int kv0 = tt * 64;
    if (kv0 > qw + 31) return;
    const ushort* Kd = Klds[bsel];
    const ushort* Vd = Vlds[bsel];
    ushort* Pw = Plds[w];
    // ---- QK^T: 32 q-rows x 64 kv ----
    floatx4 sfr[2][4];
#pragma unroll
    for (int m = 0; m < 2; m++)
#pragma unroll
      for (int n = 0; n < 4; n++) sfr[m][n] = (floatx4)(0.0f);
#pragma unroll
    for (int kc = 0; kc < 4; kc++) {
#pragma unroll
      for (int n = 0; n < 4; n++) {
        const int krow = n * 16 + L;
        const int ck = ((kc << 2) + g) ^ L;
        short8 kf = *(const short8*)((const char*)Kd + krow * 256 + ck * 16);
        sfr[0][n] = __builtin_amdgcn_mfma_f32_16x16x32_bf16(qf[0][kc], kf, sfr[0][n], 0, 0, 0);
        sfr[1][n] = __builtin_amdgcn_mfma_f32_16x16x32_bf16(qf[1][kc], kf, sfr[1][n], 0, 0, 0);
      }
    }
    // ---- scale + causal mask + row max ----
    float mx[2][4];
#pragma unroll
    for (int m = 0; m < 2; m++)
#pragma unroll
      for (int r = 0; r < 4; r++) {
        const int qg = qw + m * 16 + g * 4 + r;
        float mm = -3.0e38f;
#pragma unroll
        for (int n = 0; n < 4; n++) {
          float v = sfr[m][n][r] * ATT_SCALE;
          if (kv0 + n * 16 + L > qg) v = -1e30f;
          sfr[m][n][r] = v;
          mm = fmaxf(mm, v);
        }
        mx[m][r] = mm;
      }
#pragma unroll
    for (int off = 1; off < 16; off <<= 1)
#pragma unroll
      for (int m = 0; m < 2; m++)
#pragma unroll
        for (int r = 0; r < 4; r++)
          mx[m][r] = fmaxf(mx[m][r], __shfl_xor(mx[m][r], off, 64));
    float alpha[2][4], ls[2][4];
#pragma unroll
    for (int m = 0; m < 2; m++)
#pragma unroll
      for (int r = 0; r < 4; r++) {
        float mnew = fmaxf(mrun[m][r], mx[m][r]);
        alpha[m][r] = __expf(mrun[m][r] - mnew);
        mrun[m][r] = mnew;
        ls[m][r] = 0.0f;
      }
#pragma unroll
    for (int m = 0; m < 2; m++)
#pragma unroll
      for (int n = 0; n < 4; n++)
#pragma unroll
        for (int r = 0; r < 4; r++) {
          float p = __expf(sfr[m][n][r] - mrun[m][r]);
          sfr[m][n][r] = p;
          ls[m][r] += p;
        }
#pragma unroll
    for (int off = 1; off < 16; off <<= 1)
#pragma unroll
      for (int m = 0; m < 2; m++)
#pragma unroll
        for (int r = 0; r < 4; r++)
          ls[m][r] += __shfl_xor(ls[m][r], off, 64);
#pragma unroll
    for (int m = 0; m < 2; m++)
#pragma unroll
      for (int r = 0; r < 4; r++)
        lrun[m][r] = lrun[m][r] * alpha[m][r] + ls[m][r];
    // ---- P -> per-wave LDS (bf16), swizzled: elem (R,c) at R*64 + (c ^ ((R&3)<<4)) ----
#pragma unroll
    for (int m = 0; m < 2; m++)
#pragma unroll
      for (int n = 0; n < 4; n++)
#pragma unroll
        for (int r = 0; r < 4; r++) {
          const int R = m * 16 + g * 4 + r;
          const int col = n * 16 + L;
          Pw[R * 64 + (col ^ (r << 4))] = f2b(sfr[m][n][r]);
        }
    // ---- rescale O ----
#pragma unroll
    for (int m = 0; m < 2; m++)
#pragma unroll
      for (int dt = 0; dt < 8; dt++)
#pragma unroll
        for (int r = 0; r < 4; r++) o[m][dt][r] *= alpha[m][r];
    // ---- PV ----
#pragma unroll
    for (int kc = 0; kc < 2; kc++) {
      short8 pf[2];
#pragma unroll
      for (int m = 0; m < 2; m++) {
        const int R = m * 16 + L;
        const int C = kc * 32 + g * 8;
        pf[m] = *(const short8*)&Pw[R * 64 + (C ^ ((L & 3) << 4))];
      }
#pragma unroll
      for (int dt = 0; dt < 8; dt++) {
        const int d = dt * 16 + L;
        const int gp = ((kc << 2) + g) ^ (d & 7);
        short8 vf = *(const short8*)((const char*)Vd + d * 128 + gp * 16);
        o[0][dt] = __builtin_amdgcn_mfma_f32_16x16x32_bf16(pf[0], vf, o[0][dt], 0, 0, 0);
        o[1][dt] = __builtin_amdgcn_mfma_f32_16x16x32_bf16(pf[1], vf, o[1][dt], 0, 0, 0);
      }
    }
  };

  auto epilogue = [&](int qw) {
#pragma unroll
    for (int m = 0; m < 2; m++)
#pragma unroll
      for (int r = 0; r < 4; r++) {
        const float inv = 1.0f / lrun[m][r];
        const int qg = qw + m * 16 + g * 4 + r;
#pragma unroll
        for (int dt = 0; dt < 8; dt++)
          O[(size_t)(b * 2048 + qg) * 4096 + h * 128 + dt * 16 + L] =
              f2b(o[m][dt][r] * inv);
      }
  };

  int s = 0;
  stage(0);
  __syncthreads();

  int qw = qtA * 128 + w * 32;
  init_pass(qw);
  for (int i = 0; i < nA; ++i, ++s) {
    if (s + 1 < total) stage(s + 1);
    compute(i, s & 1, qw);
    __syncthreads();
  }
  epilogue(qw);

  qw = qtB * 128 + w * 32;
  init_pass(qw);
  for (int i = 0; i < nB; ++i, ++s) {
    if (s + 1 < total) stage(s + 1);
    compute(i, s & 1, qw);
    __syncthreads();
  }
  epilogue(qw);
}

// ---------------- launch ----------------
extern "C" void kernel_launch(void* const* d_in, const int* in_sizes, int n_in,
                              void* d_out, int out_size, void* d_ws, size_t ws_size,
                              hipStream_t stream) {
  const float* x = (const float*)d_in[0];
  const float* rc = (const float*)d_in[1];
  const float* rs = (const float*)d_in[2];
  const float* wqkv = (const float*)d_in[3];
  const float* wproj = (const float*)d_in[4];
  float* out = (float*)d_out;

  // workspace layout (ushort elements)
  ushort* xb = (ushort*)d_ws;            // 16777216  (x bf16; reused late for W_proj bf16)
  ushort* wqkvb = xb + 16777216;         // 25165824
  ushort* qkvb = wqkvb + 25165824;       // 25165824  (qkv; reused for attn out)
  ushort* Qb = qkvb + 25165824;          // 16777216
  ushort* Kb = Qb + 16777216;            // 4194304
  ushort* Vt = Kb + 4194304;             // 4194304   (V^T [B,HK,D,T])
  ushort* wprojb = xb;                   // alias: x dead after GEMM1
  ushort* aob = qkvb;                    // alias: qkv dead after vtrans

  cvt_kernel<<<2048, 256, 0, stream>>>(x, xb, 16777216L);
  cvt_kernel<<<2048, 256, 0, stream>>>(wqkv, wqkvb, 25165824L);
  gemm_pipe<128, 1><<<768, 512, 0, stream>>>(xb, wqkvb, nullptr, qkvb, 4096, 6144, 4096);
  rope_kernel<<<4096, 256, 0, stream>>>(qkvb, rc, rs, Qb, Kb);
  vtrans_kernel<<<512, 256, 0, stream>>>(qkvb, Vt);
  attn_kernel<<<512, 256, 0, stream>>>(Qb, Kb, Vt, aob);
  cvt_kernel<<<2048, 256, 0, stream>>>(wproj, wprojb, 16777216L);
  gemm_pipe<128, 0><<<512, 512, 0, stream>>>(aob, wprojb, out, nullptr, 4096, 4096, 4096);
}

// Round 7
// 534.814 us; speedup vs baseline: 1.2393x; 1.2393x over previous
//
#include <hip/hip_runtime.h>
#include <hip/hip_bf16.h>

typedef __attribute__((ext_vector_type(8))) short short8;
typedef __attribute__((ext_vector_type(4))) short short4v;
typedef __attribute__((ext_vector_type(4))) float floatx4;

__device__ __forceinline__ float b2f(ushort u) {
  unsigned x = ((unsigned)u) << 16;
  return __builtin_bit_cast(float, x);
}
__device__ __forceinline__ ushort f2b(float f) {
  unsigned x = __builtin_bit_cast(unsigned, f);
  x += 0x7fffu + ((x >> 16) & 1u);
  return (ushort)(x >> 16);
}

__device__ __forceinline__ void gload_lds16(const void* g, void* l) {
  __builtin_amdgcn_global_load_lds(
      (const __attribute__((address_space(1))) unsigned int*)g,
      (__attribute__((address_space(3))) unsigned int*)l, 16, 0, 0);
}

// ---------------- f32 -> bf16 conversion ----------------
__global__ __launch_bounds__(256) void cvt_kernel(const float* __restrict__ in,
                                                  ushort* __restrict__ out, long n) {
  long i0 = ((long)blockIdx.x * 256 + threadIdx.x) * 4;
  long stride = (long)gridDim.x * 256 * 4;
  for (long i = i0; i < n; i += stride) {
    float4 v = *(const float4*)(in + i);
    ushort4 u;
    u.x = f2b(v.x); u.y = f2b(v.y); u.z = f2b(v.z); u.w = f2b(v.w);
    *(ushort4*)(out + i) = u;
  }
}

// ---------------- pipelined 256xBN GEMM: C[M,N] = A[M,K] * B[N,K]^T ----------------
// r5 structure (proven 186/92 us): 8 waves (2Mx4N), BK=64, double-buffered LDS, ONE
// barrier + ONE vmcnt(0) per K-tile (__syncthreads). Frag ds_reads software-pipelined
// one phase ahead. Row-XOR chunk swizzle both sides. Per-tile time ~3470 cyc is within
// 5% of the m201-class plain-HIP floor (~3300) -- do not re-tinker the wait structure.
template <int BN, int OUTBF16>
__global__ __launch_bounds__(512, 2)
void gemm_pipe(const ushort* __restrict__ A, const ushort* __restrict__ B,
               float* __restrict__ Cf, ushort* __restrict__ Cb,
               int M, int N, int K) {
  constexpr int BNF = BN / 64;                      // B frags per wave (wave N = BN/4)
  __shared__ __align__(16) ushort sA[2][256 * 64];  // [buf][row*64 + k]
  __shared__ __align__(16) ushort sB[2][BN * 64];
  const int t = threadIdx.x;
  const int lane = t & 63;
  const int L = lane & 15, g = lane >> 4;
  const int w = t >> 6;
  const int wr = w >> 2, wc = w & 3;   // 2 x 4 wave grid; per-wave C = 128 x BN/4
  const int ntn = N / BN;
  const int nwg = gridDim.x;
  const int wg = blockIdx.x;
  const int swz = (wg & 7) * (nwg >> 3) + (wg >> 3);  // bijective: nwg % 8 == 0
  const int m0 = (swz / ntn) << 8;
  const int n0 = (swz % ntn) * BN;

  floatx4 acc[8][BNF];
#pragma unroll
  for (int i = 0; i < 8; i++)
#pragma unroll
    for (int j = 0; j < BNF; j++) acc[i][j] = (floatx4)(0.0f);

  const ushort* Ab = A + (size_t)m0 * K;
  const ushort* Bb = B + (size_t)n0 * K;

  // stage one full K-tile (256 rows A + BN rows B, 64 k) linear-dest, src swizzled
  auto stage_tile = [&](const ushort* Ag, const ushort* Bg, int buf) {
#pragma unroll
    for (int j = 0; j < 4; j++) {
      const int c = j * 512 + t;            // 0..2047 16B chunks
      const int row = c >> 3, ch = c & 7;
      const int kc = ch ^ (row & 7);        // source-side swizzle
      gload_lds16(Ag + (size_t)row * K + kc * 8, (char*)&sA[buf][0] + c * 16);
    }
#pragma unroll
    for (int j = 0; j < BN / 64; j++) {
      const int c = j * 512 + t;            // 0..BN*8-1
      const int row = c >> 3, ch = c & 7;
      const int kc = ch ^ (row & 7);
      gload_lds16(Bg + (size_t)row * K + kc * 8, (char*)&sB[buf][0] + c * 16);
    }
  };
  // frag reads with matching XOR (read-side swizzle)
  auto rdA = [&](int buf, int mh, int kc16, short8* dst) {
#pragma unroll
    for (int i = 0; i < 4; i++) {
      const int row = wr * 128 + mh * 64 + i * 16 + L;
      const int ch = (kc16 * 4 + g) ^ (row & 7);
      dst[i] = *(const short8*)((const char*)&sA[buf][0] + row * 128 + ch * 16);
    }
  };
  auto rdB = [&](int buf, int kc16, short8* dst) {
#pragma unroll
    for (int i = 0; i < BNF; i++) {
      const int row = wc * (BN / 4) + i * 16 + L;
      const int ch = (kc16 * 4 + g) ^ (row & 7);
      dst[i] = *(const short8*)((const char*)&sB[buf][0] + row * 128 + ch * 16);
    }
  };

  short8 a0[4], a1[4], b0[BNF], b1[BNF];

  auto mfmaN = [&](short8* af, short8* bf, int accbase, int cnt) {
    __builtin_amdgcn_s_setprio(1);
    for (int i = 0; i < cnt; i++)
#pragma unroll
      for (int nf = 0; nf < BNF; nf++)
        acc[accbase + i][nf] =
            __builtin_amdgcn_mfma_f32_16x16x32_bf16(af[i], bf[nf], acc[accbase + i][nf], 0, 0, 0);
    __builtin_amdgcn_s_setprio(0);
  };

  const int NT = K >> 6;
  // prologue: stage tile 0, then preload its first-phase frags
  stage_tile(Ab, Bb, 0);
  __syncthreads();
  rdA(0, 0, 0, a0);
  rdB(0, 0, b0);

  for (int T = 0; T < NT; ++T) {
    const int p = T & 1, q = p ^ 1;
    const bool more = (T + 1 < NT);
    if (more) stage_tile(Ab + (T + 1) * 64, Bb + (T + 1) * 64, q);
    rdA(p, 1, 0, a1);               // reads overlap mfma below (prev-phase regs)
    mfmaN(a0, b0, 0, 4);            // (kc0, mh0)
    rdA(p, 0, 1, a0);
    rdB(p, 1, b1);
    mfmaN(a1, b0, 4, 4);            // (kc0, mh1)
    rdA(p, 1, 1, a1);
    mfmaN(a0, b1, 0, 4);            // (kc1, mh0)
    mfmaN(a1, b1, 4, 2);            // (kc1, mh1) first half
    __syncthreads();                // vmcnt(0)+barrier: T+1 stages landed, p-reads done
    if (more) {                     // next tile's first-phase frags from q, overlapped
      rdA(q, 0, 0, a0);
      rdB(q, 0, b0);
    }
    mfmaN(a1 + 2, b1, 6, 2);        // (kc1, mh1) second half covers the q-reads
  }

#pragma unroll
  for (int mf = 0; mf < 8; mf++)
#pragma unroll
    for (int nf = 0; nf < BNF; nf++)
#pragma unroll
      for (int r = 0; r < 4; r++) {
        const int row = m0 + wr * 128 + mf * 16 + g * 4 + r;
        const int col = n0 + wc * (BN / 4) + nf * 16 + L;
        if (OUTBF16)
          Cb[(size_t)row * N + col] = f2b(acc[mf][nf][r]);
        else
          Cf[(size_t)row * N + col] = acc[mf][nf][r];
      }
}

// ---------------- RoPE + split qkv -> Q[B,H,T,D], K[B,HK,T,D] ----------------
__global__ __launch_bounds__(256)
void rope_kernel(const ushort* __restrict__ qkv, const float* __restrict__ cosp,
                 const float* __restrict__ sinp, ushort* __restrict__ Qo,
                 ushort* __restrict__ Ko) {
  const int row = blockIdx.x;            // b*2048 + t
  const int b = row >> 11, tt = row & 2047;
  const int i = threadIdx.x;
  const ushort* qr = qkv + (size_t)row * 6144;

  const int jb = (i & 7) * 8;            // d offset within lower half [0,64)
  float cs[8], sn[8];
  *(float4*)&cs[0] = *(const float4*)(cosp + tt * 128 + jb);
  *(float4*)&cs[4] = *(const float4*)(cosp + tt * 128 + jb + 4);
  *(float4*)&sn[0] = *(const float4*)(sinp + tt * 128 + jb);
  *(float4*)&sn[4] = *(const float4*)(sinp + tt * 128 + jb + 4);

  {  // Q: 32 heads x 8 chunks -> 256 threads
    const int hh = i >> 3;
    short8 lo = *(const short8*)(qr + hh * 128 + jb);
    short8 hi = *(const short8*)(qr + hh * 128 + 64 + jb);
    short8 olo, ohi;
#pragma unroll
    for (int e = 0; e < 8; e++) {
      float fl = b2f((ushort)lo[e]), fh = b2f((ushort)hi[e]);
      olo[e] = (short)f2b(fl * cs[e] - fh * sn[e]);
      ohi[e] = (short)f2b(fh * cs[e] + fl * sn[e]);
    }
    ushort* dst = Qo + ((size_t)(b * 32 + hh) * 2048 + tt) * 128 + jb;
    *(short8*)dst = olo;
    *(short8*)(dst + 64) = ohi;
  }
  if (i < 64) {  // K: 8 kv-heads x 8 chunks
    const int hkk = i >> 3;
    short8 lo = *(const short8*)(qr + 4096 + hkk * 128 + jb);
    short8 hi = *(const short8*)(qr + 4096 + hkk * 128 + 64 + jb);
    short8 olo, ohi;
#pragma unroll
    for (int e = 0; e < 8; e++) {
      float fl = b2f((ushort)lo[e]), fh = b2f((ushort)hi[e]);
      olo[e] = (short)f2b(fl * cs[e] - fh * sn[e]);
      ohi[e] = (short)f2b(fh * cs[e] + fl * sn[e]);
    }
    ushort* dst = Ko + ((size_t)(b * 8 + hkk) * 2048 + tt) * 128 + jb;
    *(short8*)dst = olo;
    *(short8*)(dst + 64) = ohi;
  }
}

// ---------------- V transpose: qkv V slice -> Vt[B,HK,D,T] ----------------
__global__ __launch_bounds__(256)
void vtrans_kernel(const ushort* __restrict__ qkv, ushort* __restrict__ Vt) {
  // grid: B * HK * (T/64) = 512
  const int bx = blockIdx.x;
  const int t0 = (bx & 31) * 64;
  const int hk = (bx >> 5) & 7;
  const int b = bx >> 8;
  const int i = threadIdx.x;
  const int tq = i & 15;           // t-quad within 64
  const int dn = i >> 4;           // d-octet (16 of them)
  const ushort* src = qkv + ((size_t)(b * 2048 + t0 + tq * 4)) * 6144 + 5120 + hk * 128 + dn * 8;
  short8 v0 = *(const short8*)(src);
  short8 v1 = *(const short8*)(src + 6144);
  short8 v2 = *(const short8*)(src + 12288);
  short8 v3 = *(const short8*)(src + 18432);
  ushort* dst = Vt + ((size_t)(b * 8 + hk) * 128 + dn * 8) * 2048 + t0 + tq * 4;
#pragma unroll
  for (int e = 0; e < 8; e++) {
    short4v pk;
    pk[0] = v0[e]; pk[1] = v1[e]; pk[2] = v2[e]; pk[3] = v3[e];
    *(short4v*)(dst + (size_t)e * 2048) = pk;
  }
}

// ---------------- causal GQA flash attention ----------------
// 512 blocks. XCD-aware decode: hk = bx&7 (= XCD under round-robin dispatch), so each
// XCD's 64 co-resident blocks stream only 2 KV sets (2MB, fits its 4MB L2) -> staging
// becomes L2-hit instead of 32x-redundant LLC traffic. Block does q-tiles qtA=pair,
// qtB=15-pair sequentially over one double-buffered KV prefetch sequence (34 tiles).
#define ATT_SCALE 0.08838834764831845f

__global__ __launch_bounds__(256, 2)
void attn_kernel(const ushort* __restrict__ Q, const ushort* __restrict__ Kg,
                 const ushort* __restrict__ Vtg, ushort* __restrict__ O) {
  __shared__ __align__(16) ushort Klds[2][64 * 128];   // [kv][d], chunk-XOR swizzled
  __shared__ __align__(16) ushort Vlds[2][128 * 64];   // [d][kv], chunk-XOR swizzled
  __shared__ __align__(16) ushort Plds[4][32 * 64];    // per-wave P, col^(r<<4) swizzle
  const int t = threadIdx.x, lane = t & 63, w = t >> 6;
  const int bx = blockIdx.x;
  const int hk = bx & 7;            // XCD id under bx%8 round-robin
  const int qh = (bx >> 3) & 3;
  const int b = (bx >> 5) & 1;
  const int pair = bx >> 6;
  const int h = hk * 4 + qh;
  const int qtA = pair, qtB = 15 - pair;
  const int nA = (qtA + 1) * 2, nB = (qtB + 1) * 2;
  const int total = nA + nB;  // 34

  const ushort* Qp = Q + ((size_t)(b * 32 + h) * 2048) * 128;
  const ushort* Kp = Kg + ((size_t)(b * 8 + hk) * 2048) * 128;
  const ushort* Vp = Vtg + ((size_t)(b * 8 + hk) * 128) * 2048;

  const int L = lane & 15, g = lane >> 4;

  auto stage = [&](int s) {
    const int tt = (s < nA) ? s : s - nA;
    const int kv0 = tt * 64;
    ushort* Kd = Klds[s & 1];
    ushort* Vd = Vlds[s & 1];
#pragma unroll
    for (int j = 0; j < 4; j++) {
      const int c = j * 256 + t;
      const int krow = c >> 4, kcol = c & 15;
      gload_lds16(Kp + (size_t)(kv0 + krow) * 128 + ((kcol ^ (krow & 15)) << 3),
                  (char*)Kd + c * 16);
    }
#pragma unroll
    for (int j = 0; j < 4; j++) {
      const int c = j * 256 + t;
      const int d = c >> 3, tc = c & 7;
      gload_lds16(Vp + (size_t)d * 2048 + kv0 + ((tc ^ (d & 7)) << 3),
                  (char*)Vd + c * 16);
    }
  };

  short8 qf[2][4];
  floatx4 o[2][8];
  float mrun[2][4], lrun[2][4];

  auto init_pass = [&](int qw) {
#pragma unroll
    for (int m = 0; m < 2; m++) {
#pragma unroll
      for (int kc = 0; kc < 4; kc++)
        qf[m][kc] = *(const short8*)(Qp + (size_t)(qw + m * 16 + L) * 128 + kc * 32 + g * 8);
#pragma unroll
      for (int dt = 0; dt < 8; dt++) o[m][dt] = (floatx4)(0.0f);
#pragma unroll
      for (int r = 0; r < 4; r++) { mrun[m][r] = -3.0e38f; lrun[m][r] = 0.0f; }
    }
  };

  auto compute = [&](int tt, int bsel, int qw) {
    const int kv0 = tt * 64;
    if (kv0 > qw + 31) return;
    const ushort* Kd = Klds[bsel];
    const ushort* Vd = Vlds[bsel];
    ushort* Pw = Plds[w];
    // ---- QK^T: 32 q-rows x 64 kv ----
    floatx4 sfr[2][4];
#pragma unroll
    for (int m = 0; m < 2; m++)
#pragma unroll
      for (int n = 0; n < 4; n++) sfr[m][n] = (floatx4)(0.0f);
#pragma unroll
    for (int kc = 0; kc < 4; kc++) {
#pragma unroll
      for (int n = 0; n < 4; n++) {
        const int krow = n * 16 + L;
        const int ck = ((kc << 2) + g) ^ L;
        short8 kf = *(const short8*)((const char*)Kd + krow * 256 + ck * 16);
        sfr[0][n] = __builtin_amdgcn_mfma_f32_16x16x32_bf16(qf[0][kc], kf, sfr[0][n], 0, 0, 0);
        sfr[1][n] = __builtin_amdgcn_mfma_f32_16x16x32_bf16(qf[1][kc], kf, sfr[1][n], 0, 0, 0);
      }
    }
    // ---- scale + causal mask + row max ----
    float mx[2][4];
#pragma unroll
    for (int m = 0; m < 2; m++)
#pragma unroll
      for (int r = 0; r < 4; r++) {
        const int qg = qw + m * 16 + g * 4 + r;
        float mm = -3.0e38f;
#pragma unroll
        for (int n = 0; n < 4; n++) {
          float v = sfr[m][n][r] * ATT_SCALE;
          if (kv0 + n * 16 + L > qg) v = -1e30f;
          sfr[m][n][r] = v;
          mm = fmaxf(mm, v);
        }
        mx[m][r] = mm;
      }
#pragma unroll
    for (int off = 1; off < 16; off <<= 1)
#pragma unroll
      for (int m = 0; m < 2; m++)
#pragma unroll
        for (int r = 0; r < 4; r++)
          mx[m][r] = fmaxf(mx[m][r], __shfl_xor(mx[m][r], off, 64));
    float alpha[2][4], ls[2][4];
#pragma unroll
    for (int m = 0; m < 2; m++)
#pragma unroll
      for (int r = 0; r < 4; r++) {
        float mnew = fmaxf(mrun[m][r], mx[m][r]);
        alpha[m][r] = __expf(mrun[m][r] - mnew);
        mrun[m][r] = mnew;
        ls[m][r] = 0.0f;
      }
#pragma unroll
    for (int m = 0; m < 2; m++)
#pragma unroll
      for (int n = 0; n < 4; n++)
#pragma unroll
        for (int r = 0; r < 4; r++) {
          float p = __expf(sfr[m][n][r] - mrun[m][r]);
          sfr[m][n][r] = p;
          ls[m][r] += p;
        }
#pragma unroll
    for (int off = 1; off < 16; off <<= 1)
#pragma unroll
      for (int m = 0; m < 2; m++)
#pragma unroll
        for (int r = 0; r < 4; r++)
          ls[m][r] += __shfl_xor(ls[m][r], off, 64);
#pragma unroll
    for (int m = 0; m < 2; m++)
#pragma unroll
      for (int r = 0; r < 4; r++)
        lrun[m][r] = lrun[m][r] * alpha[m][r] + ls[m][r];
    // ---- P -> per-wave LDS (bf16), swizzled: elem (R,c) at R*64 + (c ^ ((R&3)<<4)) ----
#pragma unroll
    for (int m = 0; m < 2; m++)
#pragma unroll
      for (int n = 0; n < 4; n++)
#pragma unroll
        for (int r = 0; r < 4; r++) {
          const int R = m * 16 + g * 4 + r;
          const int col = n * 16 + L;
          Pw[R * 64 + (col ^ (r << 4))] = f2b(sfr[m][n][r]);
        }
    // ---- rescale O ----
#pragma unroll
    for (int m = 0; m < 2; m++)
#pragma unroll
      for (int dt = 0; dt < 8; dt++)
#pragma unroll
        for (int r = 0; r < 4; r++) o[m][dt][r] *= alpha[m][r];
    // ---- PV ----
#pragma unroll
    for (int kc = 0; kc < 2; kc++) {
      short8 pf[2];
#pragma unroll
      for (int m = 0; m < 2; m++) {
        const int R = m * 16 + L;
        const int C = kc * 32 + g * 8;
        pf[m] = *(const short8*)&Pw[R * 64 + (C ^ ((L & 3) << 4))];
      }
#pragma unroll
      for (int dt = 0; dt < 8; dt++) {
        const int d = dt * 16 + L;
        const int gp = ((kc << 2) + g) ^ (d & 7);
        short8 vf = *(const short8*)((const char*)Vd + d * 128 + gp * 16);
        o[0][dt] = __builtin_amdgcn_mfma_f32_16x16x32_bf16(pf[0], vf, o[0][dt], 0, 0, 0);
        o[1][dt] = __builtin_amdgcn_mfma_f32_16x16x32_bf16(pf[1], vf, o[1][dt], 0, 0, 0);
      }
    }
  };

  auto epilogue = [&](int qw) {
#pragma unroll
    for (int m = 0; m < 2; m++)
#pragma unroll
      for (int r = 0; r < 4; r++) {
        const float inv = 1.0f / lrun[m][r];
        const int qg = qw + m * 16 + g * 4 + r;
#pragma unroll
        for (int dt = 0; dt < 8; dt++)
          O[(size_t)(b * 2048 + qg) * 4096 + h * 128 + dt * 16 + L] =
              f2b(o[m][dt][r] * inv);
      }
  };

  int s = 0;
  stage(0);
  __syncthreads();

  int qw = qtA * 128 + w * 32;
  init_pass(qw);
  for (int i = 0; i < nA; ++i, ++s) {
    if (s + 1 < total) stage(s + 1);
    compute(i, s & 1, qw);
    __syncthreads();
  }
  epilogue(qw);

  qw = qtB * 128 + w * 32;
  init_pass(qw);
  for (int i = 0; i < nB; ++i, ++s) {
    if (s + 1 < total) stage(s + 1);
    compute(i, s & 1, qw);
    __syncthreads();
  }
  epilogue(qw);
}

// ---------------- launch ----------------
extern "C" void kernel_launch(void* const* d_in, const int* in_sizes, int n_in,
                              void* d_out, int out_size, void* d_ws, size_t ws_size,
                              hipStream_t stream) {
  const float* x = (const float*)d_in[0];
  const float* rc = (const float*)d_in[1];
  const float* rs = (const float*)d_in[2];
  const float* wqkv = (const float*)d_in[3];
  const float* wproj = (const float*)d_in[4];
  float* out = (float*)d_out;

  // workspace layout (ushort elements)
  ushort* xb = (ushort*)d_ws;            // 16777216  (x bf16; reused late for W_proj bf16)
  ushort* wqkvb = xb + 16777216;         // 25165824
  ushort* qkvb = wqkvb + 25165824;       // 25165824  (qkv; reused for attn out)
  ushort* Qb = qkvb + 25165824;          // 16777216
  ushort* Kb = Qb + 16777216;            // 4194304
  ushort* Vt = Kb + 4194304;             // 4194304   (V^T [B,HK,D,T])
  ushort* wprojb = xb;                   // alias: x dead after GEMM1
  ushort* aob = qkvb;                    // alias: qkv dead after vtrans

  cvt_kernel<<<2048, 256, 0, stream>>>(x, xb, 16777216L);
  cvt_kernel<<<2048, 256, 0, stream>>>(wqkv, wqkvb, 25165824L);
  gemm_pipe<192, 1><<<512, 512, 0, stream>>>(xb, wqkvb, nullptr, qkvb, 4096, 6144, 4096);
  rope_kernel<<<4096, 256, 0, stream>>>(qkvb, rc, rs, Qb, Kb);
  vtrans_kernel<<<512, 256, 0, stream>>>(qkvb, Vt);
  attn_kernel<<<512, 256, 0, stream>>>(Qb, Kb, Vt, aob);
  cvt_kernel<<<2048, 256, 0, stream>>>(wproj, wprojb, 16777216L);
  gemm_pipe<256, 0><<<256, 512, 0, stream>>>(aob, wprojb, out, nullptr, 4096, 4096, 4096);
}

// Round 10
// 474.010 us; speedup vs baseline: 1.3983x; 1.1283x over previous
//
#include <hip/hip_runtime.h>
#include <hip/hip_bf16.h>

typedef __attribute__((ext_vector_type(8))) short short8;
typedef __attribute__((ext_vector_type(4))) short short4v;
typedef __attribute__((ext_vector_type(4))) float floatx4;
typedef __attribute__((ext_vector_type(16))) float floatx16;
typedef __attribute__((ext_vector_type(4))) unsigned int uintx4;

__device__ __forceinline__ float b2f(ushort u) {
  unsigned x = ((unsigned)u) << 16;
  return __builtin_bit_cast(float, x);
}
__device__ __forceinline__ ushort f2b(float f) {
  unsigned x = __builtin_bit_cast(unsigned, f);
  x += 0x7fffu + ((x >> 16) & 1u);
  return (ushort)(x >> 16);
}

__device__ __forceinline__ void gload_lds16(const void* g, void* l) {
  __builtin_amdgcn_global_load_lds(
      (const __attribute__((address_space(1))) unsigned int*)g,
      (__attribute__((address_space(3))) unsigned int*)l, 16, 0, 0);
}

// P-fragment build (T12 variant, semantics-independent): 8 f32 P-values
// (acc regs r0..r7 of one 16-kv half-block) -> bf16x8 B-operand fragment.
// Lane layout before: lo lane (hi=0) holds kv {0,1,2,3, 8,9,10,11}(+q), hi lane
// holds kv {4..7, 12..15}. B-operand needs lo: kv 0..7, hi: kv 8..15. Build via
// cvt_pk pairs + shfl_xor(32) half-exchange + per-lane select (no permlane
// direction assumption).
__device__ __forceinline__ short8 mkpa8(float p0, float p1, float p2, float p3,
                                        float p4, float p5, float p6, float p7,
                                        bool hi) {
  unsigned a0, a1, b0, b1;
  asm("v_cvt_pk_bf16_f32 %0, %1, %2" : "=v"(a0) : "v"(p0), "v"(p1));
  asm("v_cvt_pk_bf16_f32 %0, %1, %2" : "=v"(a1) : "v"(p2), "v"(p3));
  asm("v_cvt_pk_bf16_f32 %0, %1, %2" : "=v"(b0) : "v"(p4), "v"(p5));
  asm("v_cvt_pk_bf16_f32 %0, %1, %2" : "=v"(b1) : "v"(p6), "v"(p7));
  unsigned sa0 = (unsigned)__shfl_xor((int)a0, 32, 64);
  unsigned sa1 = (unsigned)__shfl_xor((int)a1, 32, 64);
  unsigned sb0 = (unsigned)__shfl_xor((int)b0, 32, 64);
  unsigned sb1 = (unsigned)__shfl_xor((int)b1, 32, 64);
  // F0 = {lo: a0 (kv0,1), hi: partner b0 (kv8,9)}
  // F1 = {lo: a1 (kv2,3), hi: partner b1 (kv10,11)}
  // F2 = {lo: partner a0 (kv4,5), hi: b0 (kv12,13)}
  // F3 = {lo: partner a1 (kv6,7), hi: b1 (kv14,15)}
  uintx4 u;
  u[0] = hi ? sb0 : a0;
  u[1] = hi ? sb1 : a1;
  u[2] = hi ? b0 : sa0;
  u[3] = hi ? b1 : sa1;
  return __builtin_bit_cast(short8, u);
}

// ---------------- f32 -> bf16 conversion ----------------
__global__ __launch_bounds__(256) void cvt_kernel(const float* __restrict__ in,
                                                  ushort* __restrict__ out, long n) {
  long i0 = ((long)blockIdx.x * 256 + threadIdx.x) * 4;
  long stride = (long)gridDim.x * 256 * 4;
  for (long i = i0; i < n; i += stride) {
    float4 v = *(const float4*)(in + i);
    ushort4 u;
    u.x = f2b(v.x); u.y = f2b(v.y); u.z = f2b(v.z); u.w = f2b(v.w);
    *(ushort4*)(out + i) = u;
  }
}

// ---------------- pipelined 256xBN GEMM: C[M,N] = A[M,K] * B[N,K]^T ----------------
// r5 structure (proven 186/92 us). Do not re-tinker the wait structure.
template <int BN, int OUTBF16>
__global__ __launch_bounds__(512, 2)
void gemm_pipe(const ushort* __restrict__ A, const ushort* __restrict__ B,
               float* __restrict__ Cf, ushort* __restrict__ Cb,
               int M, int N, int K) {
  constexpr int BNF = BN / 64;
  __shared__ __align__(16) ushort sA[2][256 * 64];
  __shared__ __align__(16) ushort sB[2][BN * 64];
  const int t = threadIdx.x;
  const int lane = t & 63;
  const int L = lane & 15, g = lane >> 4;
  const int w = t >> 6;
  const int wr = w >> 2, wc = w & 3;
  const int ntn = N / BN;
  const int nwg = gridDim.x;
  const int wg = blockIdx.x;
  const int swz = (wg & 7) * (nwg >> 3) + (wg >> 3);
  const int m0 = (swz / ntn) << 8;
  const int n0 = (swz % ntn) * BN;

  floatx4 acc[8][BNF];
#pragma unroll
  for (int i = 0; i < 8; i++)
#pragma unroll
    for (int j = 0; j < BNF; j++) acc[i][j] = (floatx4)(0.0f);

  const ushort* Ab = A + (size_t)m0 * K;
  const ushort* Bb = B + (size_t)n0 * K;

  auto stage_tile = [&](const ushort* Ag, const ushort* Bg, int buf) {
#pragma unroll
    for (int j = 0; j < 4; j++) {
      const int c = j * 512 + t;
      const int row = c >> 3, ch = c & 7;
      const int kc = ch ^ (row & 7);
      gload_lds16(Ag + (size_t)row * K + kc * 8, (char*)&sA[buf][0] + c * 16);
    }
#pragma unroll
    for (int j = 0; j < BN / 64; j++) {
      const int c = j * 512 + t;
      const int row = c >> 3, ch = c & 7;
      const int kc = ch ^ (row & 7);
      gload_lds16(Bg + (size_t)row * K + kc * 8, (char*)&sB[buf][0] + c * 16);
    }
  };
  auto rdA = [&](int buf, int mh, int kc16, short8* dst) {
#pragma unroll
    for (int i = 0; i < 4; i++) {
      const int row = wr * 128 + mh * 64 + i * 16 + L;
      const int ch = (kc16 * 4 + g) ^ (row & 7);
      dst[i] = *(const short8*)((const char*)&sA[buf][0] + row * 128 + ch * 16);
    }
  };
  auto rdB = [&](int buf, int kc16, short8* dst) {
#pragma unroll
    for (int i = 0; i < BNF; i++) {
      const int row = wc * (BN / 4) + i * 16 + L;
      const int ch = (kc16 * 4 + g) ^ (row & 7);
      dst[i] = *(const short8*)((const char*)&sB[buf][0] + row * 128 + ch * 16);
    }
  };

  short8 a0[4], a1[4], b0[BNF], b1[BNF];

  auto mfmaN = [&](short8* af, short8* bf, int accbase, int cnt) {
    __builtin_amdgcn_s_setprio(1);
    for (int i = 0; i < cnt; i++)
#pragma unroll
      for (int nf = 0; nf < BNF; nf++)
        acc[accbase + i][nf] =
            __builtin_amdgcn_mfma_f32_16x16x32_bf16(af[i], bf[nf], acc[accbase + i][nf], 0, 0, 0);
    __builtin_amdgcn_s_setprio(0);
  };

  const int NT = K >> 6;
  stage_tile(Ab, Bb, 0);
  __syncthreads();
  rdA(0, 0, 0, a0);
  rdB(0, 0, b0);

  for (int T = 0; T < NT; ++T) {
    const int p = T & 1, q = p ^ 1;
    const bool more = (T + 1 < NT);
    if (more) stage_tile(Ab + (T + 1) * 64, Bb + (T + 1) * 64, q);
    rdA(p, 1, 0, a1);
    mfmaN(a0, b0, 0, 4);
    rdA(p, 0, 1, a0);
    rdB(p, 1, b1);
    mfmaN(a1, b0, 4, 4);
    rdA(p, 1, 1, a1);
    mfmaN(a0, b1, 0, 4);
    mfmaN(a1, b1, 4, 2);
    __syncthreads();
    if (more) {
      rdA(q, 0, 0, a0);
      rdB(q, 0, b0);
    }
    mfmaN(a1 + 2, b1, 6, 2);
  }

#pragma unroll
  for (int mf = 0; mf < 8; mf++)
#pragma unroll
    for (int nf = 0; nf < BNF; nf++)
#pragma unroll
      for (int r = 0; r < 4; r++) {
        const int row = m0 + wr * 128 + mf * 16 + g * 4 + r;
        const int col = n0 + wc * (BN / 4) + nf * 16 + L;
        if (OUTBF16)
          Cb[(size_t)row * N + col] = f2b(acc[mf][nf][r]);
        else
          Cf[(size_t)row * N + col] = acc[mf][nf][r];
      }
}

// ---------------- RoPE + split qkv -> Q[B,H,T,D], K[B,HK,T,D] ----------------
__global__ __launch_bounds__(256)
void rope_kernel(const ushort* __restrict__ qkv, const float* __restrict__ cosp,
                 const float* __restrict__ sinp, ushort* __restrict__ Qo,
                 ushort* __restrict__ Ko) {
  const int row = blockIdx.x;            // b*2048 + t
  const int b = row >> 11, tt = row & 2047;
  const int i = threadIdx.x;
  const ushort* qr = qkv + (size_t)row * 6144;

  const int jb = (i & 7) * 8;
  float cs[8], sn[8];
  *(float4*)&cs[0] = *(const float4*)(cosp + tt * 128 + jb);
  *(float4*)&cs[4] = *(const float4*)(cosp + tt * 128 + jb + 4);
  *(float4*)&sn[0] = *(const float4*)(sinp + tt * 128 + jb);
  *(float4*)&sn[4] = *(const float4*)(sinp + tt * 128 + jb + 4);

  {
    const int hh = i >> 3;
    short8 lo = *(const short8*)(qr + hh * 128 + jb);
    short8 hi = *(const short8*)(qr + hh * 128 + 64 + jb);
    short8 olo, ohi;
#pragma unroll
    for (int e = 0; e < 8; e++) {
      float fl = b2f((ushort)lo[e]), fh = b2f((ushort)hi[e]);
      olo[e] = (short)f2b(fl * cs[e] - fh * sn[e]);
      ohi[e] = (short)f2b(fh * cs[e] + fl * sn[e]);
    }
    ushort* dst = Qo + ((size_t)(b * 32 + hh) * 2048 + tt) * 128 + jb;
    *(short8*)dst = olo;
    *(short8*)(dst + 64) = ohi;
  }
  if (i < 64) {
    const int hkk = i >> 3;
    short8 lo = *(const short8*)(qr + 4096 + hkk * 128 + jb);
    short8 hi = *(const short8*)(qr + 4096 + hkk * 128 + 64 + jb);
    short8 olo, ohi;
#pragma unroll
    for (int e = 0; e < 8; e++) {
      float fl = b2f((ushort)lo[e]), fh = b2f((ushort)hi[e]);
      olo[e] = (short)f2b(fl * cs[e] - fh * sn[e]);
      ohi[e] = (short)f2b(fh * cs[e] + fl * sn[e]);
    }
    ushort* dst = Ko + ((size_t)(b * 8 + hkk) * 2048 + tt) * 128 + jb;
    *(short8*)dst = olo;
    *(short8*)(dst + 64) = ohi;
  }
}

// ---------------- V transpose: qkv V slice -> Vt[B,HK,D,T] ----------------
__global__ __launch_bounds__(256)
void vtrans_kernel(const ushort* __restrict__ qkv, ushort* __restrict__ Vt) {
  const int bx = blockIdx.x;
  const int t0 = (bx & 31) * 64;
  const int hk = (bx >> 5) & 7;
  const int b = bx >> 8;
  const int i = threadIdx.x;
  const int tq = i & 15;
  const int dn = i >> 4;
  const ushort* src = qkv + ((size_t)(b * 2048 + t0 + tq * 4)) * 6144 + 5120 + hk * 128 + dn * 8;
  short8 v0 = *(const short8*)(src);
  short8 v1 = *(const short8*)(src + 6144);
  short8 v2 = *(const short8*)(src + 12288);
  short8 v3 = *(const short8*)(src + 18432);
  ushort* dst = Vt + ((size_t)(b * 8 + hk) * 128 + dn * 8) * 2048 + t0 + tq * 4;
#pragma unroll
  for (int e = 0; e < 8; e++) {
    short4v pk;
    pk[0] = v0[e]; pk[1] = v1[e]; pk[2] = v2[e]; pk[3] = v3[e];
    *(short4v*)(dst + (size_t)e * 2048) = pk;
  }
}

// ---------------- causal GQA flash attention (swapped-operand, in-reg softmax) ----
// 512 blocks, XCD decode hk=bx&7. Per wave 32 q rows. QK^T = mfma32x32(K,Q) ->
// S[kv][q] with q=lane&31: softmax state is per-lane scalar; row-reduce = in-lane
// tree + one shfl_xor(32). P->bf16 via cvt_pk + shfl_xor half-exchange (no LDS
// round-trip). PV = mfma32x32(V^T, P) -> O[d][q] keeps q=lane&31 (scalar rescale).
// Defer-max rescale (T13). Epilogue: per-wave swizzled LDS transpose -> coalesced.
#define ATT_C2 0.1275172707611085f  /* (1/sqrt(128)) * log2(e) */

__global__ __launch_bounds__(256, 2)
void attn_kernel(const ushort* __restrict__ Q, const ushort* __restrict__ Kg,
                 const ushort* __restrict__ Vtg, ushort* __restrict__ O) {
  __shared__ __align__(16) ushort Klds[2][64 * 128];   // [kv][d], chunk-XOR swizzled
  __shared__ __align__(16) ushort Vlds[2][128 * 64];   // [d][kv], chunk-XOR swizzled
  __shared__ __align__(16) ushort Olds[4][32 * 64];    // per-wave epilogue transpose
  const int t = threadIdx.x, lane = t & 63, w = t >> 6;
  const int bx = blockIdx.x;
  const int hk = bx & 7;            // XCD id under bx%8 round-robin
  const int qh = (bx >> 3) & 3;
  const int b = (bx >> 5) & 1;
  const int pair = bx >> 6;
  const int h = hk * 4 + qh;
  const int qtA = pair, qtB = 15 - pair;
  const int nA = (qtA + 1) * 2, nB = (qtB + 1) * 2;
  const int total = nA + nB;  // 34

  const ushort* Qp = Q + ((size_t)(b * 32 + h) * 2048) * 128;
  const ushort* Kp = Kg + ((size_t)(b * 8 + hk) * 2048) * 128;
  const ushort* Vp = Vtg + ((size_t)(b * 8 + hk) * 128) * 2048;

  const int l31 = lane & 31;
  const bool hib = lane >= 32;
  const int hi = hib ? 1 : 0;

  auto stage = [&](int s) {
    const int tt = (s < nA) ? s : s - nA;
    const int kv0 = tt * 64;
    ushort* Kd = Klds[s & 1];
    ushort* Vd = Vlds[s & 1];
#pragma unroll
    for (int j = 0; j < 4; j++) {
      const int c = j * 256 + t;
      const int krow = c >> 4, kcol = c & 15;
      gload_lds16(Kp + (size_t)(kv0 + krow) * 128 + ((kcol ^ (krow & 15)) << 3),
                  (char*)Kd + c * 16);
    }
#pragma unroll
    for (int j = 0; j < 4; j++) {
      const int c = j * 256 + t;
      const int d = c >> 3, tc = c & 7;
      gload_lds16(Vp + (size_t)d * 2048 + kv0 + ((tc ^ (d & 7)) << 3),
                  (char*)Vd + c * 16);
    }
  };

  short8 qf[8];          // Q[q=lane&31][ks*16 + hi*8 + e], ks=0..7
  floatx16 o[4];         // O[d][q]: d = dblk*32 + crow(reg,hi), q = lane&31
  float mrun, lrun;

  auto init_pass = [&](int qw_) {
#pragma unroll
    for (int ks = 0; ks < 8; ks++)
      qf[ks] = *(const short8*)(Qp + (size_t)(qw_ + l31) * 128 + ks * 16 + hi * 8);
#pragma unroll
    for (int d = 0; d < 4; d++) o[d] = (floatx16)(0.0f);
    mrun = -3.0e38f;
    lrun = 0.0f;
  };

  auto compute = [&](int tt, int bsel, int qw_) {
    const int kv0 = tt * 64;
    if (kv0 > qw_ + 31) return;
    const ushort* Kd = Klds[bsel];
    const ushort* Vd = Vlds[bsel];
    // ---- QK^T: S[kv][q], two 32-kv blocks ----
    floatx16 s0 = (floatx16)(0.0f), s1 = (floatx16)(0.0f);
#pragma unroll
    for (int ks = 0; ks < 8; ks++) {
      const int gc = ks * 2 + hi;
      const int r0 = l31;
      short8 kf0 = *(const short8*)((const char*)Kd + r0 * 256 + ((gc ^ (r0 & 15)) * 16));
      s0 = __builtin_amdgcn_mfma_f32_32x32x16_bf16(kf0, qf[ks], s0, 0, 0, 0);
      const int r1 = 32 + l31;
      short8 kf1 = *(const short8*)((const char*)Kd + r1 * 256 + ((gc ^ (r1 & 15)) * 16));
      s1 = __builtin_amdgcn_mfma_f32_32x32x16_bf16(kf1, qf[ks], s1, 0, 0, 0);
    }
    const int qg = qw_ + l31;
    if (kv0 + 63 > qw_) {  // boundary tiles only (wave-uniform)
#pragma unroll
      for (int r = 0; r < 16; r++) {
        const int kvr = (r & 3) + 8 * (r >> 2) + 4 * hi;
        if (kv0 + kvr > qg) s0[r] = -3.0e38f;
        if (kv0 + 32 + kvr > qg) s1[r] = -3.0e38f;
      }
    }
    // ---- row max (in-lane tree + one swap) ----
    float m1 = fmaxf(s0[0], s0[1]);
#pragma unroll
    for (int r = 2; r < 16; r++) m1 = fmaxf(m1, s0[r]);
#pragma unroll
    for (int r = 0; r < 16; r++) m1 = fmaxf(m1, s1[r]);
    m1 = fmaxf(m1, __shfl_xor(m1, 32, 64));
    // ---- defer-max rescale (T13): THR = 8 / C2 in raw-score units ----
    if (!__all(m1 - mrun <= 62.73f)) {
      const float mnew = fmaxf(mrun, m1);
      const float alpha = __builtin_amdgcn_exp2f((mrun - mnew) * ATT_C2);
      lrun *= alpha;
#pragma unroll
      for (int d = 0; d < 4; d++)
#pragma unroll
        for (int r = 0; r < 16; r++) o[d][r] *= alpha;
      mrun = mnew;
    }
    // ---- P = 2^((s - m)*c2), row sum ----
    float ls = 0.0f;
#pragma unroll
    for (int r = 0; r < 16; r++) {
      float p = __builtin_amdgcn_exp2f((s0[r] - mrun) * ATT_C2);
      s0[r] = p; ls += p;
    }
#pragma unroll
    for (int r = 0; r < 16; r++) {
      float p = __builtin_amdgcn_exp2f((s1[r] - mrun) * ATT_C2);
      s1[r] = p; ls += p;
    }
    ls += __shfl_xor(ls, 32, 64);
    lrun += ls;
    // ---- P fragments (shfl-based half-exchange) ----
    short8 pa00 = mkpa8(s0[0], s0[1], s0[2], s0[3], s0[4], s0[5], s0[6], s0[7], hib);
    short8 pa01 = mkpa8(s0[8], s0[9], s0[10], s0[11], s0[12], s0[13], s0[14], s0[15], hib);
    short8 pa10 = mkpa8(s1[0], s1[1], s1[2], s1[3], s1[4], s1[5], s1[6], s1[7], hib);
    short8 pa11 = mkpa8(s1[8], s1[9], s1[10], s1[11], s1[12], s1[13], s1[14], s1[15], hib);
    // ---- PV: O[d][q] += V^T x P ----
#pragma unroll
    for (int kvb = 0; kvb < 2; kvb++)
#pragma unroll
      for (int sh = 0; sh < 2; sh++) {
        const short8 pa = (kvb == 0) ? (sh == 0 ? pa00 : pa01) : (sh == 0 ? pa10 : pa11);
        const int gc = kvb * 4 + sh * 2 + hi;
#pragma unroll
        for (int d = 0; d < 4; d++) {
          const int vr = d * 32 + l31;
          short8 vf = *(const short8*)((const char*)Vd + vr * 128 + ((gc ^ (vr & 7)) * 16));
          o[d] = __builtin_amdgcn_mfma_f32_32x32x16_bf16(vf, pa, o[d], 0, 0, 0);
        }
      }
  };

  auto epilogue = [&](int qw_) {
    const float inv = 1.0f / lrun;
    ushort* Ow = Olds[w];
    const int q = l31;
#pragma unroll
    for (int half = 0; half < 2; half++) {
      // write 64 d-values (2 dblks) for own q, swizzled [q][d ^ ((q&7)<<3)]
#pragma unroll
      for (int dd = 0; dd < 2; dd++) {
        const int dblk = half * 2 + dd;
#pragma unroll
        for (int rp = 0; rp < 8; rp++) {
          const int r0 = rp * 2;
          const int d0 = dd * 32 + (r0 & 3) + 8 * (r0 >> 2) + 4 * hi;
          unsigned pk;
          asm("v_cvt_pk_bf16_f32 %0, %1, %2" : "=v"(pk)
              : "v"(o[dblk][r0] * inv), "v"(o[dblk][r0 + 1] * inv));
          *(unsigned*)&Ow[q * 64 + (d0 ^ ((q & 7) << 3))] = pk;
        }
      }
      // read out rows, coalesced global store (8 q-rows x 8 segs x 16B per instr)
#pragma unroll
      for (int qs = 0; qs < 4; qs++) {
        const int qq = qs * 8 + (lane >> 3);
        const int seg = lane & 7;
        short8 v = *(const short8*)&Ow[qq * 64 + ((seg * 8) ^ ((qq & 7) << 3))];
        *(short8*)&O[(size_t)(b * 2048 + qw_ + qq) * 4096 + h * 128 + half * 64 + seg * 8] = v;
      }
    }
  };

  int s = 0;
  stage(0);
  __syncthreads();

  int qw = qtA * 128 + w * 32;
  init_pass(qw);
  for (int i = 0; i < nA; ++i, ++s) {
    if (s + 1 < total) stage(s + 1);
    compute(i, s & 1, qw);
    __syncthreads();
  }
  epilogue(qw);

  qw = qtB * 128 + w * 32;
  init_pass(qw);
  for (int i = 0; i < nB; ++i, ++s) {
    if (s + 1 < total) stage(s + 1);
    compute(i, s & 1, qw);
    __syncthreads();
  }
  epilogue(qw);
}

// ---------------- launch ----------------
extern "C" void kernel_launch(void* const* d_in, const int* in_sizes, int n_in,
                              void* d_out, int out_size, void* d_ws, size_t ws_size,
                              hipStream_t stream) {
  const float* x = (const float*)d_in[0];
  const float* rc = (const float*)d_in[1];
  const float* rs = (const float*)d_in[2];
  const float* wqkv = (const float*)d_in[3];
  const float* wproj = (const float*)d_in[4];
  float* out = (float*)d_out;

  // workspace layout (ushort elements)
  ushort* xb = (ushort*)d_ws;            // 16777216  (x bf16; reused late for W_proj bf16)
  ushort* wqkvb = xb + 16777216;         // 25165824
  ushort* qkvb = wqkvb + 25165824;       // 25165824  (qkv; reused for attn out)
  ushort* Qb = qkvb + 25165824;          // 16777216
  ushort* Kb = Qb + 16777216;            // 4194304
  ushort* Vt = Kb + 4194304;             // 4194304   (V^T [B,HK,D,T])
  ushort* wprojb = xb;                   // alias: x dead after GEMM1
  ushort* aob = qkvb;                    // alias: qkv dead after vtrans

  cvt_kernel<<<2048, 256, 0, stream>>>(x, xb, 16777216L);
  cvt_kernel<<<2048, 256, 0, stream>>>(wqkv, wqkvb, 25165824L);
  gemm_pipe<192, 1><<<512, 512, 0, stream>>>(xb, wqkvb, nullptr, qkvb, 4096, 6144, 4096);
  rope_kernel<<<4096, 256, 0, stream>>>(qkvb, rc, rs, Qb, Kb);
  vtrans_kernel<<<512, 256, 0, stream>>>(qkvb, Vt);
  attn_kernel<<<512, 256, 0, stream>>>(Qb, Kb, Vt, aob);
  cvt_kernel<<<2048, 256, 0, stream>>>(wproj, wprojb, 16777216L);
  gemm_pipe<256, 0><<<256, 512, 0, stream>>>(aob, wprojb, out, nullptr, 4096, 4096, 4096);
}

// Round 11
// 470.127 us; speedup vs baseline: 1.4098x; 1.0083x over previous
//
#include <hip/hip_runtime.h>
#include <hip/hip_bf16.h>

typedef __attribute__((ext_vector_type(8))) short short8;
typedef __attribute__((ext_vector_type(4))) short short4v;
typedef __attribute__((ext_vector_type(4))) float floatx4;
typedef __attribute__((ext_vector_type(16))) float floatx16;
typedef __attribute__((ext_vector_type(4))) unsigned int uintx4;

__device__ __forceinline__ float b2f(ushort u) {
  unsigned x = ((unsigned)u) << 16;
  return __builtin_bit_cast(float, x);
}
__device__ __forceinline__ ushort f2b(float f) {
  unsigned x = __builtin_bit_cast(unsigned, f);
  x += 0x7fffu + ((x >> 16) & 1u);
  return (ushort)(x >> 16);
}

__device__ __forceinline__ void gload_lds16(const void* g, void* l) {
  __builtin_amdgcn_global_load_lds(
      (const __attribute__((address_space(1))) unsigned int*)g,
      (__attribute__((address_space(3))) unsigned int*)l, 16, 0, 0);
}

// P-fragment build (T12): 8 f32 P-values (acc regs r0..r7 of one 16-kv
// half-block) -> bf16x8 B-operand fragment, via cvt_pk + permlane32_swap.
// Lane layout before: lo lane holds kv {0,1,2,3, 8,9,10,11}, hi lane holds
// kv {4..7, 12..15} (for the same q=lane&31). permlane32_swap semantics
// (CDNA4): upper half of vdst <-> lower half of src. swap(a0,b0) gives
// a0 = {lo:(kv0,1), hi:(kv8,9)} = u0 and b0 = {lo:(kv4,5), hi:(kv12,13)} = u2
// -- both outputs usable (HK idiom). Layout itself verified by the r10 shfl
// version; only the swap replaces 4 ds_bpermute + selects per fragment.
__device__ __forceinline__ short8 mkpa8(float p0, float p1, float p2, float p3,
                                        float p4, float p5, float p6, float p7) {
  unsigned a0, a1, b0, b1;
  asm("v_cvt_pk_bf16_f32 %0, %1, %2" : "=v"(a0) : "v"(p0), "v"(p1));
  asm("v_cvt_pk_bf16_f32 %0, %1, %2" : "=v"(a1) : "v"(p2), "v"(p3));
  asm("v_cvt_pk_bf16_f32 %0, %1, %2" : "=v"(b0) : "v"(p4), "v"(p5));
  asm("v_cvt_pk_bf16_f32 %0, %1, %2" : "=v"(b1) : "v"(p6), "v"(p7));
  asm volatile("v_permlane32_swap_b32 %0, %1" : "+v"(a0), "+v"(b0));
  asm volatile("v_permlane32_swap_b32 %0, %1" : "+v"(a1), "+v"(b1));
  uintx4 u;
  u[0] = a0;  // kv 0,1 (lo) / 8,9  (hi)
  u[1] = a1;  // kv 2,3 (lo) / 10,11(hi)
  u[2] = b0;  // kv 4,5 (lo) / 12,13(hi)
  u[3] = b1;  // kv 6,7 (lo) / 14,15(hi)
  return __builtin_bit_cast(short8, u);
}

// ---------------- f32 -> bf16 conversion ----------------
__global__ __launch_bounds__(256) void cvt_kernel(const float* __restrict__ in,
                                                  ushort* __restrict__ out, long n) {
  long i0 = ((long)blockIdx.x * 256 + threadIdx.x) * 4;
  long stride = (long)gridDim.x * 256 * 4;
  for (long i = i0; i < n; i += stride) {
    float4 v = *(const float4*)(in + i);
    ushort4 u;
    u.x = f2b(v.x); u.y = f2b(v.y); u.z = f2b(v.z); u.w = f2b(v.w);
    *(ushort4*)(out + i) = u;
  }
}

// ---------------- pipelined 256xBN GEMM: C[M,N] = A[M,K] * B[N,K]^T ----------------
// r5 structure (proven 186/92 us). Do not re-tinker the wait structure.
template <int BN, int OUTBF16>
__global__ __launch_bounds__(512, 2)
void gemm_pipe(const ushort* __restrict__ A, const ushort* __restrict__ B,
               float* __restrict__ Cf, ushort* __restrict__ Cb,
               int M, int N, int K) {
  constexpr int BNF = BN / 64;
  __shared__ __align__(16) ushort sA[2][256 * 64];
  __shared__ __align__(16) ushort sB[2][BN * 64];
  const int t = threadIdx.x;
  const int lane = t & 63;
  const int L = lane & 15, g = lane >> 4;
  const int w = t >> 6;
  const int wr = w >> 2, wc = w & 3;
  const int ntn = N / BN;
  const int nwg = gridDim.x;
  const int wg = blockIdx.x;
  const int swz = (wg & 7) * (nwg >> 3) + (wg >> 3);
  const int m0 = (swz / ntn) << 8;
  const int n0 = (swz % ntn) * BN;

  floatx4 acc[8][BNF];
#pragma unroll
  for (int i = 0; i < 8; i++)
#pragma unroll
    for (int j = 0; j < BNF; j++) acc[i][j] = (floatx4)(0.0f);

  const ushort* Ab = A + (size_t)m0 * K;
  const ushort* Bb = B + (size_t)n0 * K;

  auto stage_tile = [&](const ushort* Ag, const ushort* Bg, int buf) {
#pragma unroll
    for (int j = 0; j < 4; j++) {
      const int c = j * 512 + t;
      const int row = c >> 3, ch = c & 7;
      const int kc = ch ^ (row & 7);
      gload_lds16(Ag + (size_t)row * K + kc * 8, (char*)&sA[buf][0] + c * 16);
    }
#pragma unroll
    for (int j = 0; j < BN / 64; j++) {
      const int c = j * 512 + t;
      const int row = c >> 3, ch = c & 7;
      const int kc = ch ^ (row & 7);
      gload_lds16(Bg + (size_t)row * K + kc * 8, (char*)&sB[buf][0] + c * 16);
    }
  };
  auto rdA = [&](int buf, int mh, int kc16, short8* dst) {
#pragma unroll
    for (int i = 0; i < 4; i++) {
      const int row = wr * 128 + mh * 64 + i * 16 + L;
      const int ch = (kc16 * 4 + g) ^ (row & 7);
      dst[i] = *(const short8*)((const char*)&sA[buf][0] + row * 128 + ch * 16);
    }
  };
  auto rdB = [&](int buf, int kc16, short8* dst) {
#pragma unroll
    for (int i = 0; i < BNF; i++) {
      const int row = wc * (BN / 4) + i * 16 + L;
      const int ch = (kc16 * 4 + g) ^ (row & 7);
      dst[i] = *(const short8*)((const char*)&sB[buf][0] + row * 128 + ch * 16);
    }
  };

  short8 a0[4], a1[4], b0[BNF], b1[BNF];

  auto mfmaN = [&](short8* af, short8* bf, int accbase, int cnt) {
    __builtin_amdgcn_s_setprio(1);
    for (int i = 0; i < cnt; i++)
#pragma unroll
      for (int nf = 0; nf < BNF; nf++)
        acc[accbase + i][nf] =
            __builtin_amdgcn_mfma_f32_16x16x32_bf16(af[i], bf[nf], acc[accbase + i][nf], 0, 0, 0);
    __builtin_amdgcn_s_setprio(0);
  };

  const int NT = K >> 6;
  stage_tile(Ab, Bb, 0);
  __syncthreads();
  rdA(0, 0, 0, a0);
  rdB(0, 0, b0);

  for (int T = 0; T < NT; ++T) {
    const int p = T & 1, q = p ^ 1;
    const bool more = (T + 1 < NT);
    if (more) stage_tile(Ab + (T + 1) * 64, Bb + (T + 1) * 64, q);
    rdA(p, 1, 0, a1);
    mfmaN(a0, b0, 0, 4);
    rdA(p, 0, 1, a0);
    rdB(p, 1, b1);
    mfmaN(a1, b0, 4, 4);
    rdA(p, 1, 1, a1);
    mfmaN(a0, b1, 0, 4);
    mfmaN(a1, b1, 4, 2);
    __syncthreads();
    if (more) {
      rdA(q, 0, 0, a0);
      rdB(q, 0, b0);
    }
    mfmaN(a1 + 2, b1, 6, 2);
  }

#pragma unroll
  for (int mf = 0; mf < 8; mf++)
#pragma unroll
    for (int nf = 0; nf < BNF; nf++)
#pragma unroll
      for (int r = 0; r < 4; r++) {
        const int row = m0 + wr * 128 + mf * 16 + g * 4 + r;
        const int col = n0 + wc * (BN / 4) + nf * 16 + L;
        if (OUTBF16)
          Cb[(size_t)row * N + col] = f2b(acc[mf][nf][r]);
        else
          Cf[(size_t)row * N + col] = acc[mf][nf][r];
      }
}

// ---------------- RoPE + split qkv -> Q[B,H,T,D], K[B,HK,T,D] ----------------
__global__ __launch_bounds__(256)
void rope_kernel(const ushort* __restrict__ qkv, const float* __restrict__ cosp,
                 const float* __restrict__ sinp, ushort* __restrict__ Qo,
                 ushort* __restrict__ Ko) {
  const int row = blockIdx.x;            // b*2048 + t
  const int b = row >> 11, tt = row & 2047;
  const int i = threadIdx.x;
  const ushort* qr = qkv + (size_t)row * 6144;

  const int jb = (i & 7) * 8;
  float cs[8], sn[8];
  *(float4*)&cs[0] = *(const float4*)(cosp + tt * 128 + jb);
  *(float4*)&cs[4] = *(const float4*)(cosp + tt * 128 + jb + 4);
  *(float4*)&sn[0] = *(const float4*)(sinp + tt * 128 + jb);
  *(float4*)&sn[4] = *(const float4*)(sinp + tt * 128 + jb + 4);

  {
    const int hh = i >> 3;
    short8 lo = *(const short8*)(qr + hh * 128 + jb);
    short8 hi = *(const short8*)(qr + hh * 128 + 64 + jb);
    short8 olo, ohi;
#pragma unroll
    for (int e = 0; e < 8; e++) {
      float fl = b2f((ushort)lo[e]), fh = b2f((ushort)hi[e]);
      olo[e] = (short)f2b(fl * cs[e] - fh * sn[e]);
      ohi[e] = (short)f2b(fh * cs[e] + fl * sn[e]);
    }
    ushort* dst = Qo + ((size_t)(b * 32 + hh) * 2048 + tt) * 128 + jb;
    *(short8*)dst = olo;
    *(short8*)(dst + 64) = ohi;
  }
  if (i < 64) {
    const int hkk = i >> 3;
    short8 lo = *(const short8*)(qr + 4096 + hkk * 128 + jb);
    short8 hi = *(const short8*)(qr + 4096 + hkk * 128 + 64 + jb);
    short8 olo, ohi;
#pragma unroll
    for (int e = 0; e < 8; e++) {
      float fl = b2f((ushort)lo[e]), fh = b2f((ushort)hi[e]);
      olo[e] = (short)f2b(fl * cs[e] - fh * sn[e]);
      ohi[e] = (short)f2b(fh * cs[e] + fl * sn[e]);
    }
    ushort* dst = Ko + ((size_t)(b * 8 + hkk) * 2048 + tt) * 128 + jb;
    *(short8*)dst = olo;
    *(short8*)(dst + 64) = ohi;
  }
}

// ---------------- V transpose: qkv V slice -> Vt[B,HK,D,T] ----------------
__global__ __launch_bounds__(256)
void vtrans_kernel(const ushort* __restrict__ qkv, ushort* __restrict__ Vt) {
  const int bx = blockIdx.x;
  const int t0 = (bx & 31) * 64;
  const int hk = (bx >> 5) & 7;
  const int b = bx >> 8;
  const int i = threadIdx.x;
  const int tq = i & 15;
  const int dn = i >> 4;
  const ushort* src = qkv + ((size_t)(b * 2048 + t0 + tq * 4)) * 6144 + 5120 + hk * 128 + dn * 8;
  short8 v0 = *(const short8*)(src);
  short8 v1 = *(const short8*)(src + 6144);
  short8 v2 = *(const short8*)(src + 12288);
  short8 v3 = *(const short8*)(src + 18432);
  ushort* dst = Vt + ((size_t)(b * 8 + hk) * 128 + dn * 8) * 2048 + t0 + tq * 4;
#pragma unroll
  for (int e = 0; e < 8; e++) {
    short4v pk;
    pk[0] = v0[e]; pk[1] = v1[e]; pk[2] = v2[e]; pk[3] = v3[e];
    *(short4v*)(dst + (size_t)e * 2048) = pk;
  }
}

// ---------------- causal GQA flash attention (swapped-operand, in-reg softmax) ----
// 512 blocks, XCD decode hk=bx&7. Per wave 32 q rows. QK^T = mfma32x32(K,Q) ->
// S[kv][q] with q=lane&31: softmax state is per-lane scalar; row-reduce = in-lane
// tree + one shfl_xor(32). P->bf16 via cvt_pk + permlane32_swap (no LDS round-trip).
// PV = mfma32x32(V^T, P) -> O[d][q] keeps q=lane&31 (scalar rescale). Defer-max
// rescale (T13). setprio around MFMA clusters (T5). Epilogue: per-wave swizzled
// LDS transpose -> coalesced stores.
#define ATT_C2 0.1275172707611085f  /* (1/sqrt(128)) * log2(e) */

__global__ __launch_bounds__(256, 2)
void attn_kernel(const ushort* __restrict__ Q, const ushort* __restrict__ Kg,
                 const ushort* __restrict__ Vtg, ushort* __restrict__ O) {
  __shared__ __align__(16) ushort Klds[2][64 * 128];   // [kv][d], chunk-XOR swizzled
  __shared__ __align__(16) ushort Vlds[2][128 * 64];   // [d][kv], chunk-XOR swizzled
  __shared__ __align__(16) ushort Olds[4][32 * 64];    // per-wave epilogue transpose
  const int t = threadIdx.x, lane = t & 63, w = t >> 6;
  const int bx = blockIdx.x;
  const int hk = bx & 7;            // XCD id under bx%8 round-robin
  const int qh = (bx >> 3) & 3;
  const int b = (bx >> 5) & 1;
  const int pair = bx >> 6;
  const int h = hk * 4 + qh;
  const int qtA = pair, qtB = 15 - pair;
  const int nA = (qtA + 1) * 2, nB = (qtB + 1) * 2;
  const int total = nA + nB;  // 34

  const ushort* Qp = Q + ((size_t)(b * 32 + h) * 2048) * 128;
  const ushort* Kp = Kg + ((size_t)(b * 8 + hk) * 2048) * 128;
  const ushort* Vp = Vtg + ((size_t)(b * 8 + hk) * 128) * 2048;

  const int l31 = lane & 31;
  const int hi = lane >> 5;

  auto stage = [&](int s) {
    const int tt = (s < nA) ? s : s - nA;
    const int kv0 = tt * 64;
    ushort* Kd = Klds[s & 1];
    ushort* Vd = Vlds[s & 1];
#pragma unroll
    for (int j = 0; j < 4; j++) {
      const int c = j * 256 + t;
      const int krow = c >> 4, kcol = c & 15;
      gload_lds16(Kp + (size_t)(kv0 + krow) * 128 + ((kcol ^ (krow & 15)) << 3),
                  (char*)Kd + c * 16);
    }
#pragma unroll
    for (int j = 0; j < 4; j++) {
      const int c = j * 256 + t;
      const int d = c >> 3, tc = c & 7;
      gload_lds16(Vp + (size_t)d * 2048 + kv0 + ((tc ^ (d & 7)) << 3),
                  (char*)Vd + c * 16);
    }
  };

  short8 qf[8];          // Q[q=lane&31][ks*16 + hi*8 + e], ks=0..7
  floatx16 o[4];         // O[d][q]: d = dblk*32 + crow(reg,hi), q = lane&31
  float mrun, lrun;

  auto init_pass = [&](int qw_) {
#pragma unroll
    for (int ks = 0; ks < 8; ks++)
      qf[ks] = *(const short8*)(Qp + (size_t)(qw_ + l31) * 128 + ks * 16 + hi * 8);
#pragma unroll
    for (int d = 0; d < 4; d++) o[d] = (floatx16)(0.0f);
    mrun = -3.0e38f;
    lrun = 0.0f;
  };

  auto compute = [&](int tt, int bsel, int qw_) {
    const int kv0 = tt * 64;
    if (kv0 > qw_ + 31) return;
    const ushort* Kd = Klds[bsel];
    const ushort* Vd = Vlds[bsel];
    // ---- QK^T: S[kv][q], two 32-kv blocks ----
    floatx16 s0 = (floatx16)(0.0f), s1 = (floatx16)(0.0f);
    __builtin_amdgcn_s_setprio(1);
#pragma unroll
    for (int ks = 0; ks < 8; ks++) {
      const int gc = ks * 2 + hi;
      const int r0 = l31;
      short8 kf0 = *(const short8*)((const char*)Kd + r0 * 256 + ((gc ^ (r0 & 15)) * 16));
      s0 = __builtin_amdgcn_mfma_f32_32x32x16_bf16(kf0, qf[ks], s0, 0, 0, 0);
      const int r1 = 32 + l31;
      short8 kf1 = *(const short8*)((const char*)Kd + r1 * 256 + ((gc ^ (r1 & 15)) * 16));
      s1 = __builtin_amdgcn_mfma_f32_32x32x16_bf16(kf1, qf[ks], s1, 0, 0, 0);
    }
    __builtin_amdgcn_s_setprio(0);
    const int qg = qw_ + l31;
    if (kv0 + 63 > qw_) {  // boundary tiles only (wave-uniform)
#pragma unroll
      for (int r = 0; r < 16; r++) {
        const int kvr = (r & 3) + 8 * (r >> 2) + 4 * hi;
        if (kv0 + kvr > qg) s0[r] = -3.0e38f;
        if (kv0 + 32 + kvr > qg) s1[r] = -3.0e38f;
      }
    }
    // ---- row max (in-lane tree + one swap) ----
    float m1 = fmaxf(s0[0], s0[1]);
#pragma unroll
    for (int r = 2; r < 16; r++) m1 = fmaxf(m1, s0[r]);
#pragma unroll
    for (int r = 0; r < 16; r++) m1 = fmaxf(m1, s1[r]);
    m1 = fmaxf(m1, __shfl_xor(m1, 32, 64));
    // ---- defer-max rescale (T13): THR = 8 / C2 in raw-score units ----
    if (!__all(m1 - mrun <= 62.73f)) {
      const float mnew = fmaxf(mrun, m1);
      const float alpha = __builtin_amdgcn_exp2f((mrun - mnew) * ATT_C2);
      lrun *= alpha;
#pragma unroll
      for (int d = 0; d < 4; d++)
#pragma unroll
        for (int r = 0; r < 16; r++) o[d][r] *= alpha;
      mrun = mnew;
    }
    // ---- P = 2^((s - m)*c2), row sum ----
    float ls = 0.0f;
#pragma unroll
    for (int r = 0; r < 16; r++) {
      float p = __builtin_amdgcn_exp2f((s0[r] - mrun) * ATT_C2);
      s0[r] = p; ls += p;
    }
#pragma unroll
    for (int r = 0; r < 16; r++) {
      float p = __builtin_amdgcn_exp2f((s1[r] - mrun) * ATT_C2);
      s1[r] = p; ls += p;
    }
    ls += __shfl_xor(ls, 32, 64);
    lrun += ls;
    // ---- P fragments (cvt_pk + permlane32_swap) ----
    short8 pa00 = mkpa8(s0[0], s0[1], s0[2], s0[3], s0[4], s0[5], s0[6], s0[7]);
    short8 pa01 = mkpa8(s0[8], s0[9], s0[10], s0[11], s0[12], s0[13], s0[14], s0[15]);
    short8 pa10 = mkpa8(s1[0], s1[1], s1[2], s1[3], s1[4], s1[5], s1[6], s1[7]);
    short8 pa11 = mkpa8(s1[8], s1[9], s1[10], s1[11], s1[12], s1[13], s1[14], s1[15]);
    // ---- PV: O[d][q] += V^T x P ----
    __builtin_amdgcn_s_setprio(1);
#pragma unroll
    for (int kvb = 0; kvb < 2; kvb++)
#pragma unroll
      for (int sh = 0; sh < 2; sh++) {
        const short8 pa = (kvb == 0) ? (sh == 0 ? pa00 : pa01) : (sh == 0 ? pa10 : pa11);
        const int gc = kvb * 4 + sh * 2 + hi;
#pragma unroll
        for (int d = 0; d < 4; d++) {
          const int vr = d * 32 + l31;
          short8 vf = *(const short8*)((const char*)Vd + vr * 128 + ((gc ^ (vr & 7)) * 16));
          o[d] = __builtin_amdgcn_mfma_f32_32x32x16_bf16(vf, pa, o[d], 0, 0, 0);
        }
      }
    __builtin_amdgcn_s_setprio(0);
  };

  auto epilogue = [&](int qw_) {
    const float inv = 1.0f / lrun;
    ushort* Ow = Olds[w];
    const int q = l31;
#pragma unroll
    for (int half = 0; half < 2; half++) {
      // write 64 d-values (2 dblks) for own q, swizzled [q][d ^ ((q&7)<<3)]
#pragma unroll
      for (int dd = 0; dd < 2; dd++) {
        const int dblk = half * 2 + dd;
#pragma unroll
        for (int rp = 0; rp < 8; rp++) {
          const int r0 = rp * 2;
          const int d0 = dd * 32 + (r0 & 3) + 8 * (r0 >> 2) + 4 * hi;
          unsigned pk;
          asm("v_cvt_pk_bf16_f32 %0, %1, %2" : "=v"(pk)
              : "v"(o[dblk][r0] * inv), "v"(o[dblk][r0 + 1] * inv));
          *(unsigned*)&Ow[q * 64 + (d0 ^ ((q & 7) << 3))] = pk;
        }
      }
      // read out rows, coalesced global store (8 q-rows x 8 segs x 16B per instr)
#pragma unroll
      for (int qs = 0; qs < 4; qs++) {
        const int qq = qs * 8 + (lane >> 3);
        const int seg = lane & 7;
        short8 v = *(const short8*)&Ow[qq * 64 + ((seg * 8) ^ ((qq & 7) << 3))];
        *(short8*)&O[(size_t)(b * 2048 + qw_ + qq) * 4096 + h * 128 + half * 64 + seg * 8] = v;
      }
    }
  };

  int s = 0;
  stage(0);
  __syncthreads();

  int qw = qtA * 128 + w * 32;
  init_pass(qw);
  for (int i = 0; i < nA; ++i, ++s) {
    if (s + 1 < total) stage(s + 1);
    compute(i, s & 1, qw);
    __syncthreads();
  }
  epilogue(qw);

  qw = qtB * 128 + w * 32;
  init_pass(qw);
  for (int i = 0; i < nB; ++i, ++s) {
    if (s + 1 < total) stage(s + 1);
    compute(i, s & 1, qw);
    __syncthreads();
  }
  epilogue(qw);
}

// ---------------- launch ----------------
extern "C" void kernel_launch(void* const* d_in, const int* in_sizes, int n_in,
                              void* d_out, int out_size, void* d_ws, size_t ws_size,
                              hipStream_t stream) {
  const float* x = (const float*)d_in[0];
  const float* rc = (const float*)d_in[1];
  const float* rs = (const float*)d_in[2];
  const float* wqkv = (const float*)d_in[3];
  const float* wproj = (const float*)d_in[4];
  float* out = (float*)d_out;

  // workspace layout (ushort elements)
  ushort* xb = (ushort*)d_ws;            // 16777216  (x bf16; reused late for W_proj bf16)
  ushort* wqkvb = xb + 16777216;         // 25165824
  ushort* qkvb = wqkvb + 25165824;       // 25165824  (qkv; reused for attn out)
  ushort* Qb = qkvb + 25165824;          // 16777216
  ushort* Kb = Qb + 16777216;            // 4194304
  ushort* Vt = Kb + 4194304;             // 4194304   (V^T [B,HK,D,T])
  ushort* wprojb = xb;                   // alias: x dead after GEMM1
  ushort* aob = qkvb;                    // alias: qkv dead after vtrans

  cvt_kernel<<<2048, 256, 0, stream>>>(x, xb, 16777216L);
  cvt_kernel<<<2048, 256, 0, stream>>>(wqkv, wqkvb, 25165824L);
  gemm_pipe<192, 1><<<512, 512, 0, stream>>>(xb, wqkvb, nullptr, qkvb, 4096, 6144, 4096);
  rope_kernel<<<4096, 256, 0, stream>>>(qkvb, rc, rs, Qb, Kb);
  vtrans_kernel<<<512, 256, 0, stream>>>(qkvb, Vt);
  attn_kernel<<<512, 256, 0, stream>>>(Qb, Kb, Vt, aob);
  cvt_kernel<<<2048, 256, 0, stream>>>(wproj, wprojb, 16777216L);
  gemm_pipe<256, 0><<<256, 512, 0, stream>>>(aob, wprojb, out, nullptr, 4096, 4096, 4096);
}